// Round 12
// baseline (198.203 us; speedup 1.0000x reference)
//
#include <hip/hip_runtime.h>
#include <hip/hip_fp16.h>
#include <math.h>

#define S 256
#define A 180
#define B 4
#define PMAX 310           // max row stride in halves (even); 264*310*2 = 163,680 B
#define NROWS 264          // 4 zero rows + 256 image rows + 4 zero rows

// Kernel 1: inscribed-circle mask (dx^2+dy^2 <= 128^2 == sqrt<=128) + fp32->fp16.
__global__ void radon_mask_f16(const float* __restrict__ in, __half* __restrict__ out) {
    int idx = blockIdx.x * 256 + threadIdx.x;    // 0 .. B*S*S-1
    int p = idx & (S * S - 1);
    int y = p >> 8;
    int x = p & 255;
    int dx = x - 128, dy = y - 128;
    float v = in[idx];
    v = (dx * dx + dy * dy <= 16384) ? v : 0.0f;
    out[idx] = __float2half(v);
}

// Kernel 2: one block per (angle,batch), 1024 threads = (j, quarter-of-ray).
// Image staged into LDS at origin (+4,+4) of a 264xP tile whose border strips
// are zeroed: every tap of the d<=130.13 trimmed ray reads in-bounds LDS, and
// out-of-image corners read true zeros (identical contribution to the
// reference's zero-weight OOB corners; in-image pixels >128 from center are
// circle-masked to zero). -> the tap loop is BRANCH-FREE: no rim path, no d2
// test. Thread (j,q) covers an equal quarter of ray j's own valid range
// (balanced trip counts within a wave). Per-angle row stride P (even, 264..310)
// picked by thread 0 so the wave's lane address stride is ~odd in dwords.
__global__ __launch_bounds__(1024, 1) void radon_lds_kernel(const __half* __restrict__ img,
                                                            float* __restrict__ out) {
    __shared__ __half lds[NROWS * PMAX];         // 163,680 B
    __shared__ int sP;

    const int a = blockIdx.x;   // angle
    const int b = blockIdx.y;   // batch
    const int tid = threadIdx.x;

    float ang = (float)a * (float)(M_PI / 179.0);
    float sn, cs;
    sincosf(ang, &sn, &cs);

    // per-angle stride: lane addr stride = P*cs - sn halves; want ~odd dwords
    if (tid == 0) {
        int P = 264;
        float best = 1e9f;
        for (int cand = 264; cand <= PMAX; cand += 2) {
            float sd = 0.5f * fabsf((float)cand * cs - sn);   // dwords/lane
            float m = sd - 2.0f * floorf(sd * 0.5f);          // mod 2
            float score = fabsf(m - 1.0f);                    // 0 = odd = free
            if (score < best) { best = score; P = cand; }
        }
        sP = P;
    }
    __syncthreads();
    const int P = sP;
    const int Ph = P >> 1;       // dwords per row

    uint* l32 = (uint*)lds;
    // ---- main staging: image row y -> LDS row y+4, image dword xd -> slot xd+2
    const uint* __restrict__ src = (const uint*)(img + (size_t)b * (S * S));
#pragma unroll
    for (int k = 0; k < 32; ++k) {
        int p = k * 1024 + tid;
        int y = p >> 7;            // 128 dwords per source row
        int xd = p & 127;
        l32[(y + 4) * Ph + xd + 2] = src[p];
    }
    // ---- border zeroing (reads reach rows 1..262, dwords 0..131) ----
    {
        // (a) strip rows {0,1,2,3,260,261,262,263}, dwords 4..131 (8*128 = 1024)
        int rsel = tid >> 7;
        int r = (rsel < 4) ? rsel : (256 + rsel);
        l32[r * Ph + (tid & 127) + 4] = 0u;
        // (b) strip rows, dwords 0..3 (32 slots)
        if (tid < 32) {
            int rs = tid >> 2;
            int rr = (rs < 4) ? rs : (256 + rs);
            l32[rr * Ph + (tid & 3)] = 0u;
        }
        // (c) data rows 4..259, dwords {0,1,130,131} (256*4 = 1024)
        int rc = 4 + (tid >> 2);
        int dsel = tid & 3;
        int dd = (dsel < 2) ? dsel : (128 + dsel);
        l32[rc * Ph + dd] = 0u;
    }
    __syncthreads();

    const int j = tid & 255;
    const int q = tid >> 8;

    const float ry = (float)j - 127.5f;
    const float bx = fmaf(-sn, ry, 127.5f);
    const float by = fmaf(cs, ry, 127.5f);
    const float ry2 = ry * ry;

    // disk trim: keep i with rx^2 + ry^2 <= 16934 (~130.13^2; taps beyond are
    // provably zero). Balanced split: quarter q of THIS ray's range.
    float h = sqrtf(16934.0f - ry2);
    int ilo = max((int)ceilf(127.5f - h), 0);
    int ihi = min((int)(127.5f + h) + 1, S);
    int len = ihi - ilo;
    int lo = ilo + ((q * len) >> 2);
    int hi = ilo + (((q + 1) * len) >> 2);

    // origin at (+4,+4): tap addr = y0*P + x0 relative to origin, y0,x0 may be
    // as low as -3 (still inside the array: 4P+4 - 3P - 3 >= P+1 > 0)
    const __half* __restrict__ orig = &lds[4 * P + 4];
    const float Pf = (float)P;

    float rxs = (float)lo - 127.5f;
    float px = fmaf(cs, rxs, bx);
    float py = fmaf(sn, rxs, by);
    float acc = 0.0f;

#pragma unroll 4
    for (int i = lo; i < hi; ++i) {
        float x0f = floorf(px);
        float y0f = floorf(py);
        float wx = px - x0f;
        float wy = py - y0f;
        int addr = (int)fmaf(y0f, Pf, x0f);   // exact (integer-valued, |.| < 2^17)
        const __half* p0 = orig + addr;
        float v00 = __half2float(p0[0]);
        float v10 = __half2float(p0[1]);
        float v01 = __half2float(p0[P]);
        float v11 = __half2float(p0[P + 1]);
        float r0 = fmaf(wx, v10 - v00, v00);
        float r1 = fmaf(wx, v11 - v01, v01);
        acc = fmaf(wy, r1 - r0, acc + r0);
        px += cs;
        py += sn;
    }

    // ---- reduce the 4 quarters per j (reuse LDS after barrier) ----
    __syncthreads();
    float* red = (float*)lds;
    red[tid] = acc;
    __syncthreads();
    if (q == 0) {
        float r = red[j] + red[j + 256] + red[j + 512] + red[j + 768];
        out[((size_t)b * A + a) * S + j] = r;
    }
}

extern "C" void kernel_launch(void* const* d_in, const int* in_sizes, int n_in,
                              void* d_out, int out_size, void* d_ws, size_t ws_size,
                              hipStream_t stream) {
    const float* x = (const float*)d_in[0];
    float* out = (float*)d_out;
    __half* masked = (__half*)d_ws;  // B*S*S halves = 512 KiB

    radon_mask_f16<<<dim3((B * S * S) / 256), dim3(256), 0, stream>>>(x, masked);
    radon_lds_kernel<<<dim3(A, B), dim3(1024), 0, stream>>>(masked, out);
}

// Round 13
// 106.507 us; speedup vs baseline: 1.8609x; 1.8609x over previous
//
#include <hip/hip_runtime.h>
#include <hip/hip_fp16.h>
#include <math.h>

#define S 256
#define A 180
#define B 4
#define PMAX 310           // max row stride in halves (even); 264*310*2 = 163,680 B
#define NROWS 264          // 4 zero rows + 256 image rows + 4 zero rows

// Kernel 1: inscribed-circle mask (dx^2+dy^2 <= 128^2 == sqrt<=128) + fp32->fp16.
__global__ void radon_mask_f16(const float* __restrict__ in, __half* __restrict__ out) {
    int idx = blockIdx.x * 256 + threadIdx.x;    // 0 .. B*S*S-1
    int p = idx & (S * S - 1);
    int y = p >> 8;
    int x = p & 255;
    int dx = x - 128, dy = y - 128;
    float v = in[idx];
    v = (dx * dx + dy * dy <= 16384) ? v : 0.0f;
    out[idx] = __float2half(v);
}

// Kernel 2: R8 (69.6 us proven) + ONE change: zero-border LDS tile kills the
// rim branch. Image at origin (+4,+4) of a 264xP tile with zeroed border
// strips: every tap of the d<=130.13-trimmed ray reads in-bounds LDS, and
// out-of-image corners read true zeros (same contribution as the reference's
// zero-weight OOB corners; in-image pixels >128 from center are circle-masked
// to 0). Kept from R8 verbatim: per-thread P search, fixed i-quarters, FRESH
// per-iter px/py from i (unroll-parallel addr gen -- incremental px+=cs was
// the R11/R12 serial-chain stall), integer y0*P+x0 addressing, products-form
// accumulation.
__global__ __launch_bounds__(1024, 1) void radon_lds_kernel(const __half* __restrict__ img,
                                                            float* __restrict__ out) {
    __shared__ __half lds[NROWS * PMAX];         // 163,680 B

    const int a = blockIdx.x;   // angle
    const int b = blockIdx.y;   // batch
    const int tid = threadIdx.x;

    float ang = (float)a * (float)(M_PI / 179.0);
    float sn, cs;
    sincosf(ang, &sn, &cs);

    // per-angle stride: lane half-stride ~= P*cs - sn; want dword stride ~odd
    int P = 264;
    {
        float best = 1e9f;
        for (int cand = 264; cand <= PMAX; cand += 2) {
            float sd = 0.5f * fabsf((float)cand * cs - sn);   // dwords/lane
            float m = sd - 2.0f * floorf(sd * 0.5f);          // mod 2
            float score = fabsf(m - 1.0f);                    // 0 = odd = free
            if (score < best) { best = score; P = cand; }
        }
    }
    const int Ph = P >> 1;       // dwords per row

    uint* l32 = (uint*)lds;
    // ---- stage: image row y -> LDS row y+4; image dword xd -> slot xd+2 ----
    const uint* __restrict__ src = (const uint*)(img + (size_t)b * (S * S));
#pragma unroll
    for (int k = 0; k < 32; ++k) {
        int p = k * 1024 + tid;
        int y = p >> 7;            // 128 dwords per source row
        int xd = p & 127;
        l32[(y + 4) * Ph + xd + 2] = src[p];
    }
    // ---- border zeroing (reads reach rows 1..262, dwords 0..131) ----
    {
        // (a) strip rows {0..3, 260..263}, dwords 4..131 (8*128 = 1024 slots)
        int rsel = tid >> 7;
        int r = (rsel < 4) ? rsel : (256 + rsel);
        l32[r * Ph + (tid & 127) + 4] = 0u;
        // (b) strip rows, dwords 0..3 (32 slots)
        if (tid < 32) {
            int rs = tid >> 2;
            int rr = (rs < 4) ? rs : (256 + rs);
            l32[rr * Ph + (tid & 3)] = 0u;
        }
        // (c) data rows 4..259, dwords {0,1,130,131} (256*4 = 1024 slots)
        int rc = 4 + (tid >> 2);
        int dsel = tid & 3;
        int dd = (dsel < 2) ? dsel : (128 + dsel);
        l32[rc * Ph + dd] = 0u;
    }
    __syncthreads();

    const int j = tid & 255;
    const int iq = tid >> 8;

    const float ry = (float)j - 127.5f;
    const float bx = fmaf(-sn, ry, 127.5f);
    const float by = fmaf(cs, ry, 127.5f);
    const float ry2 = ry * ry;

    // disk trim: keep i with rx^2 + ry^2 <= 16934 (~130.13^2 > provable 130.122)
    float h = sqrtf(16934.0f - ry2);
    int ilo = (int)ceilf(127.5f - h);
    int ihi = (int)floorf(127.5f + h) + 1;
    ilo = max(max(ilo, iq * 64), 0);
    ihi = min(min(ihi, iq * 64 + 64), S);

    // origin at (+4,+4): addr = y0*P + x0, y0,x0 in [-3,257] stays in-array
    const __half* __restrict__ orig = &lds[4 * P + 4];

    float acc = 0.0f;

#pragma unroll 4
    for (int i = ilo; i < ihi; ++i) {
        float rx = (float)i - 127.5f;
        float px = fmaf(cs, rx, bx);
        float py = fmaf(sn, rx, by);

        float x0f = floorf(px);
        float y0f = floorf(py);
        float wx = px - x0f;
        float wy = py - y0f;
        int x0 = (int)x0f;
        int y0 = (int)y0f;
        float ux = 1.0f - wx;
        float uy = 1.0f - wy;
        float w00 = ux * uy;
        float w10 = wx * uy;
        float w01 = ux * wy;
        float w11 = wx * wy;

        const __half* p0 = orig + (y0 * P + x0);
        float v00 = __half2float(p0[0]);
        float v10 = __half2float(p0[1]);
        float v01 = __half2float(p0[P]);
        float v11 = __half2float(p0[P + 1]);

        acc = fmaf(w00, v00, fmaf(w10, v10, fmaf(w01, v01, fmaf(w11, v11, acc))));
    }

    // ---- reduce the 4 i-quarters per j (reuse LDS after barrier) ----
    __syncthreads();
    float* red = (float*)lds;
    red[tid] = acc;
    __syncthreads();
    if (iq == 0) {
        float r = red[j] + red[j + 256] + red[j + 512] + red[j + 768];
        out[((size_t)b * A + a) * S + j] = r;
    }
}

extern "C" void kernel_launch(void* const* d_in, const int* in_sizes, int n_in,
                              void* d_out, int out_size, void* d_ws, size_t ws_size,
                              hipStream_t stream) {
    const float* x = (const float*)d_in[0];
    float* out = (float*)d_out;
    __half* masked = (__half*)d_ws;  // B*S*S halves = 512 KiB

    radon_mask_f16<<<dim3((B * S * S) / 256), dim3(256), 0, stream>>>(x, masked);
    radon_lds_kernel<<<dim3(A, B), dim3(1024), 0, stream>>>(masked, out);
}

// Round 14
// 96.030 us; speedup vs baseline: 2.0640x; 1.1091x over previous
//
#include <hip/hip_runtime.h>
#include <hip/hip_fp16.h>
#include <math.h>

#define S 256
#define A 180
#define B 4
#define PMAX 310           // max row stride in halves (even); 264*310*2 = 163,680 B
#define NROWS 264          // 4 zero rows + 256 image rows + 4 zero rows

// Kernel 1: inscribed-circle mask (dx^2+dy^2 <= 128^2 == sqrt<=128) + fp32->fp16.
__global__ void radon_mask_f16(const float* __restrict__ in, __half* __restrict__ out) {
    int idx = blockIdx.x * 256 + threadIdx.x;    // 0 .. B*S*S-1
    int p = idx & (S * S - 1);
    int y = p >> 8;
    int x = p & 255;
    int dx = x - 128, dy = y - 128;
    float v = in[idx];
    v = (dx * dx + dy * dy <= 16384) ? v : 0.0f;
    out[idx] = __float2half(v);
}

// Kernel 2: R13 (57.6 us proven: zero-border LDS tile, branch-free tap loop,
// fresh per-iter addr gen, products accumulation) + ONE change: lane remap for
// issue balance. j = tid>>2, q = tid&3 -> a wave spans 16 consecutive j (len
// variance small) instead of 64 (20% exec-mask waste), and each ray is split
// into 4 equal-length segments (lo = ilo + q*len/4) so the 4 q-lanes of a ray
// have identical trip counts. Reduction: quarters of ray j are red[4j..4j+3],
// read back as one aligned float4.
__global__ __launch_bounds__(1024, 1) void radon_lds_kernel(const __half* __restrict__ img,
                                                            float* __restrict__ out) {
    __shared__ __half lds[NROWS * PMAX];         // 163,680 B

    const int a = blockIdx.x;   // angle
    const int b = blockIdx.y;   // batch
    const int tid = threadIdx.x;

    float ang = (float)a * (float)(M_PI / 179.0);
    float sn, cs;
    sincosf(ang, &sn, &cs);

    // per-angle stride: lane half-stride ~= P*cs - sn; want dword stride ~odd
    int P = 264;
    {
        float best = 1e9f;
        for (int cand = 264; cand <= PMAX; cand += 2) {
            float sd = 0.5f * fabsf((float)cand * cs - sn);   // dwords/lane
            float m = sd - 2.0f * floorf(sd * 0.5f);          // mod 2
            float score = fabsf(m - 1.0f);                    // 0 = odd = free
            if (score < best) { best = score; P = cand; }
        }
    }
    const int Ph = P >> 1;       // dwords per row

    uint* l32 = (uint*)lds;
    // ---- stage: image row y -> LDS row y+4; image dword xd -> slot xd+2 ----
    const uint* __restrict__ src = (const uint*)(img + (size_t)b * (S * S));
#pragma unroll
    for (int k = 0; k < 32; ++k) {
        int p = k * 1024 + tid;
        int y = p >> 7;            // 128 dwords per source row
        int xd = p & 127;
        l32[(y + 4) * Ph + xd + 2] = src[p];
    }
    // ---- border zeroing (reads reach rows 1..262, dwords 0..131) ----
    {
        // (a) strip rows {0..3, 260..263}, dwords 4..131 (8*128 = 1024 slots)
        int rsel = tid >> 7;
        int r = (rsel < 4) ? rsel : (256 + rsel);
        l32[r * Ph + (tid & 127) + 4] = 0u;
        // (b) strip rows, dwords 0..3 (32 slots)
        if (tid < 32) {
            int rs = tid >> 2;
            int rr = (rs < 4) ? rs : (256 + rs);
            l32[rr * Ph + (tid & 3)] = 0u;
        }
        // (c) data rows 4..259, dwords {0,1,130,131} (256*4 = 1024 slots)
        int rc = 4 + (tid >> 2);
        int dsel = tid & 3;
        int dd = (dsel < 2) ? dsel : (128 + dsel);
        l32[rc * Ph + dd] = 0u;
    }
    __syncthreads();

    const int j = tid >> 2;      // ray index: 16 consecutive j per wave
    const int q = tid & 3;       // ray segment (lane-minor)

    const float ry = (float)j - 127.5f;
    const float bx = fmaf(-sn, ry, 127.5f);
    const float by = fmaf(cs, ry, 127.5f);
    const float ry2 = ry * ry;

    // disk trim: keep i with rx^2 + ry^2 <= 16934 (~130.13^2 > provable 130.122)
    // then split THIS ray's range into 4 equal segments (balanced trip counts).
    float h = sqrtf(16934.0f - ry2);
    int ilo = max((int)ceilf(127.5f - h), 0);
    int ihi = min((int)floorf(127.5f + h) + 1, S);
    int len = ihi - ilo;
    int lo = ilo + ((q * len) >> 2);
    int hi = ilo + (((q + 1) * len) >> 2);

    // origin at (+4,+4): addr = y0*P + x0, y0,x0 in [-3,257] stays in-array
    const __half* __restrict__ orig = &lds[4 * P + 4];

    float acc = 0.0f;

#pragma unroll 4
    for (int i = lo; i < hi; ++i) {
        float rx = (float)i - 127.5f;
        float px = fmaf(cs, rx, bx);
        float py = fmaf(sn, rx, by);

        float x0f = floorf(px);
        float y0f = floorf(py);
        float wx = px - x0f;
        float wy = py - y0f;
        int x0 = (int)x0f;
        int y0 = (int)y0f;
        float ux = 1.0f - wx;
        float uy = 1.0f - wy;
        float w00 = ux * uy;
        float w10 = wx * uy;
        float w01 = ux * wy;
        float w11 = wx * wy;

        const __half* p0 = orig + (y0 * P + x0);
        float v00 = __half2float(p0[0]);
        float v10 = __half2float(p0[1]);
        float v01 = __half2float(p0[P]);
        float v11 = __half2float(p0[P + 1]);

        acc = fmaf(w00, v00, fmaf(w10, v10, fmaf(w01, v01, fmaf(w11, v11, acc))));
    }

    // ---- reduce the 4 segments per j (red[4j..4j+3] -> one float4) ----
    __syncthreads();
    float* red = (float*)lds;
    red[tid] = acc;
    __syncthreads();
    if (tid < 256) {
        float4 v = ((const float4*)red)[tid];
        out[((size_t)b * A + a) * S + tid] = v.x + v.y + v.z + v.w;
    }
}

extern "C" void kernel_launch(void* const* d_in, const int* in_sizes, int n_in,
                              void* d_out, int out_size, void* d_ws, size_t ws_size,
                              hipStream_t stream) {
    const float* x = (const float*)d_in[0];
    float* out = (float*)d_out;
    __half* masked = (__half*)d_ws;  // B*S*S halves = 512 KiB

    radon_mask_f16<<<dim3((B * S * S) / 256), dim3(256), 0, stream>>>(x, masked);
    radon_lds_kernel<<<dim3(A, B), dim3(1024), 0, stream>>>(masked, out);
}

// Round 15
// 92.419 us; speedup vs baseline: 2.1446x; 1.0391x over previous
//
#include <hip/hip_runtime.h>
#include <hip/hip_fp16.h>
#include <math.h>

#define S 256
#define A 180
#define B 4
#define PMAX 296   // max row stride in halves (even); 137*296*2 = 81,104 B -> 2 blocks/CU
#define NR 137     // staged rows per half-plane block

// Kernel 1: inscribed-circle mask + fp32->fp16, AND zero the output sinogram
// (out has 720*256 = 184,320 elements; this grid has 1024 blocks of 256).
__global__ void radon_mask_f16(const float* __restrict__ in, __half* __restrict__ out,
                               float* __restrict__ osino) {
    int idx = blockIdx.x * 256 + threadIdx.x;    // 0 .. B*S*S-1
    int p = idx & (S * S - 1);
    int y = p >> 8;
    int x = p & 255;
    int dx = x - 128, dy = y - 128;
    float v = in[idx];
    v = (dx * dx + dy * dy <= 16384) ? v : 0.0f;
    out[idx] = __float2half(v);
    if (idx < A * B * S) osino[idx] = 0.0f;
}

// Kernel 2: grid (A, B, 2). Block (a,b,h) owns taps whose y0=floor(py) lies in
// half-plane h (h0: y0<=127, h1: y0>=128). py is monotone non-decreasing in i
// (sin>=0 on [0,pi]), so ownership is the i-interval split at isplit, computed
// identically in both blocks -> exact partition of R14's tap set. Each block
// stages only 137 rows (its half + 4-row margins) => 81,104 B LDS => 2
// blocks/CU (8 waves/SIMD; R14's 160KB tile capped us at 4). Zero border via
// full-tile memset then data fill. Tap loop identical to R14 (branch-free,
// fresh per-iter addr gen, products accumulation, j=tid>>2 / q=tid&3 lane
// map, per-ray balanced segments). Partials combined by 2-way atomicAdd.
__global__ __launch_bounds__(1024, 8) void radon_lds_kernel(const __half* __restrict__ img,
                                                            float* __restrict__ out) {
    __shared__ __half lds[NR * PMAX];            // 81,104 B

    const int a = blockIdx.x;   // angle
    const int b = blockIdx.y;   // batch
    const int h = blockIdx.z;   // half-plane
    const int tid = threadIdx.x;

    float ang = (float)a * (float)(M_PI / 179.0);
    float sn, cs;
    sincosf(ang, &sn, &cs);

    // per-angle stride: lane half-stride ~= P*cs - sn; want dword stride ~odd
    int P = 266;
    {
        float best = 1e9f;
        for (int cand = 266; cand <= PMAX; cand += 2) {
            float sd = 0.5f * fabsf((float)cand * cs - sn);   // dwords/lane
            float m = sd - 2.0f * floorf(sd * 0.5f);          // mod 2
            float score = fabsf(m - 1.0f);                    // 0 = odd = free
            if (score < best) { best = score; P = cand; }
        }
    }
    const int Ph = P >> 1;              // dwords per row
    const int row0 = h ? 124 : -4;      // image row held in LDS row 0

    uint* l32 = (uint*)lds;
    // ---- zero the whole tile (borders become true zeros) ----
    {
        int nz = NR * Ph;
#pragma unroll
        for (int k = 0; k < 20; ++k) {
            int p = k * 1024 + tid;
            if (p < nz) l32[p] = 0u;
        }
    }
    __syncthreads();
    // ---- fill 132 data rows: img rows (h?124:0) .. +131 ----
    {
        const int r0img = h ? 124 : 0;
        const uint* __restrict__ src = (const uint*)(img + (size_t)b * (S * S));
#pragma unroll
        for (int k = 0; k < 17; ++k) {
            int p = k * 1024 + tid;
            if (p < 132 * 128) {
                int r = p >> 7;             // 0..131
                int xd = p & 127;
                int dstrow = r + (h ? 0 : 4);
                l32[dstrow * Ph + xd + 2] = src[(r0img + r) * 128 + xd];
            }
        }
    }
    __syncthreads();

    const int j = tid >> 2;      // ray index: 16 consecutive j per wave
    const int q = tid & 3;       // ray segment (lane-minor)

    const float ry = (float)j - 127.5f;
    const float bx = fmaf(-sn, ry, 127.5f);
    const float by = fmaf(cs, ry, 127.5f);
    const float ry2 = ry * ry;

    // disk trim (taps beyond d^2>16934 are provably zero)
    float hd = sqrtf(16934.0f - ry2);
    int ilo = max((int)ceilf(127.5f - hd), 0);
    int ihi = min((int)floorf(127.5f + hd) + 1, S);

    // ownership split: py(i) < 128  <=>  i < isplit. inf/NaN-safe clamp
    // (sn=0: +/-inf -> 256/0; by==128 & sn==0: NaN -> 0 -> h1 owns, y0=128 ok)
    float tsf = 127.5f + (128.0f - by) / sn;
    tsf = fminf(fmaxf(tsf, 0.0f), 256.0f);
    int isplit = (int)ceilf(tsf);
    int lo0 = h ? max(ilo, isplit) : ilo;
    int hi0 = h ? ihi : min(ihi, isplit);
    int len = max(hi0 - lo0, 0);
    int lo = lo0 + ((q * len) >> 2);
    int hi = lo0 + (((q + 1) * len) >> 2);

    // LDS index of image pixel (y0,x0): (y0 - row0)*P + (x0 + 4)
    const int base = -row0 * P + 4;

    float acc = 0.0f;

#pragma unroll 4
    for (int i = lo; i < hi; ++i) {
        float rx = (float)i - 127.5f;
        float px = fmaf(cs, rx, bx);
        float py = fmaf(sn, rx, by);

        float x0f = floorf(px);
        float y0f = floorf(py);
        float wx = px - x0f;
        float wy = py - y0f;
        int x0 = (int)x0f;
        int y0 = (int)y0f;
        float ux = 1.0f - wx;
        float uy = 1.0f - wy;
        float w00 = ux * uy;
        float w10 = wx * uy;
        float w01 = ux * wy;
        float w11 = wx * wy;

        const __half* p0 = &lds[base + y0 * P + x0];
        float v00 = __half2float(p0[0]);
        float v10 = __half2float(p0[1]);
        float v01 = __half2float(p0[P]);
        float v11 = __half2float(p0[P + 1]);

        acc = fmaf(w00, v00, fmaf(w10, v10, fmaf(w01, v01, fmaf(w11, v11, acc))));
    }

    // ---- reduce the 4 segments per j, then 2-way atomic combine ----
    __syncthreads();
    float* red = (float*)lds;
    red[tid] = acc;
    __syncthreads();
    if (tid < 256) {
        float4 v = ((const float4*)red)[tid];
        atomicAdd(&out[((size_t)b * A + a) * S + tid], v.x + v.y + v.z + v.w);
    }
}

extern "C" void kernel_launch(void* const* d_in, const int* in_sizes, int n_in,
                              void* d_out, int out_size, void* d_ws, size_t ws_size,
                              hipStream_t stream) {
    const float* x = (const float*)d_in[0];
    float* out = (float*)d_out;
    __half* masked = (__half*)d_ws;  // B*S*S halves = 512 KiB

    radon_mask_f16<<<dim3((B * S * S) / 256), dim3(256), 0, stream>>>(x, masked, out);
    radon_lds_kernel<<<dim3(A, B, 2), dim3(1024), 0, stream>>>(masked, out);
}